// Round 8
// baseline (704.060 us; speedup 1.0000x reference)
//
#include <hip/hip_runtime.h>
#include <hip/hip_bf16.h>

#define BB 4      // batch
#define SS 1023   // source length = 2T-1
#define TT 512    // window length
#define CC 1024   // embed dim
#define DD 64     // head size
#define NROW (BB*SS)    // 4092
#define PR 8            // proj rows per block
#define PBLOCKS ((NROW + PR - 1) / PR)   // 512

typedef float f4 __attribute__((ext_vector_type(4)));
typedef float f2 __attribute__((ext_vector_type(2)));

// ---------------------------------------------------------------------------
// Kernel 1: projections k|v|q = x @ [Wk|Wv|Wq].
// 512 blocks x 512 threads. PR=8 x-rows staged in 32 KB LDS (broadcast reads).
// Wave wv covers K-slice [128wv,128wv+128) in 16 groups of 8 c's; W k/v loads
// software-pipelined through two 8-wide register banks (macro-inlined,
// constant-indexed -> SROA-safe). q loads issued per-group ahead of q-FMAs,
// hidden under the k/v FMA block. k stored transposed kT[d][row].
// ---------------------------------------------------------------------------
#define LOADKV(wkX, wlX, g) \
    { \
        _Pragma("unroll") \
        for (int kk = 0; kk < 8; ++kk) { \
            const int cl = (g) * 8 + kk; \
            wkX[kk] = wkp[cl * DD]; \
            wlX[kk] = wvp[cl * DD]; \
        } \
    }

#define LOADQ(g) \
    if (needq) { \
        _Pragma("unroll") \
        for (int kk = 0; kk < 8; ++kk) wq[kk] = wqp[((g) * 8 + kk) * DD]; \
    }

#define COMPKV(wkX, wlX, g) \
    { \
        _Pragma("unroll") \
        for (int h = 0; h < 2; ++h) { \
            f4 xv[PR]; \
            _Pragma("unroll") \
            for (int r = 0; r < PR; ++r) \
                xv[r] = *(const f4*)&smem[r * CC + c0 + (g) * 8 + h * 4]; \
            _Pragma("unroll") \
            for (int kk = 0; kk < 4; ++kk) \
                _Pragma("unroll") \
                for (int r = 0; r < PR; ++r) { \
                    accK[r] = fmaf(xv[r][kk], wkX[h * 4 + kk], accK[r]); \
                    accV[r] = fmaf(xv[r][kk], wlX[h * 4 + kk], accV[r]); \
                } \
        } \
    }

#define COMPQ(g) \
    if (needq) { \
        _Pragma("unroll") \
        for (int h = 0; h < 2; ++h) { \
            f4 xv[PR]; \
            _Pragma("unroll") \
            for (int r = 0; r < PR; ++r) \
                xv[r] = *(const f4*)&smem[r * CC + c0 + (g) * 8 + h * 4]; \
            _Pragma("unroll") \
            for (int kk = 0; kk < 4; ++kk) \
                _Pragma("unroll") \
                for (int r = 0; r < PR; ++r) \
                    accQ[r] = fmaf(xv[r][kk], wq[h * 4 + kk], accQ[r]); \
        } \
    }

__global__ __launch_bounds__(512, 4) void proj_kernel(
    const float* __restrict__ x,
    const float* __restrict__ Wk,
    const float* __restrict__ Wv,
    const float* __restrict__ Wq,
    float* __restrict__ kT,     // [DD][NROW]
    float* __restrict__ vbuf,   // [NROW][DD]
    float* __restrict__ qbuf)   // [BB*TT][DD]
{
    __shared__ __align__(16) float smem[PR * CC];   // 32 KB; later red[4][1536]

    const int tid  = threadIdx.x;
    const int lane = tid & 63;
    const int wv   = tid >> 6;              // 0..7
    const int bs0  = blockIdx.x * PR;
    const int nr   = (NROW - bs0 < PR) ? (NROW - bs0) : PR;
    const int s0   = bs0 % SS;
    const bool needq = (s0 + PR - 1) >= (TT - 1);

    // ---- stage x panel: 8 rows x 1024 floats, coalesced f4 ----
    {
        const f4* xg = (const f4*)x;
        f4* xs4 = (f4*)smem;
#pragma unroll
        for (int j = 0; j < 4; ++j) {
            const int idx = tid + j * 512;         // 0..2047
            const int r = idx >> 8, c4 = idx & 255;
            int g = bs0 + r; if (g > NROW - 1) g = NROW - 1;
            xs4[idx] = xg[(size_t)g * (CC / 4) + c4];
        }
    }
    __syncthreads();

    float accK[PR], accV[PR], accQ[PR];
#pragma unroll
    for (int r = 0; r < PR; ++r) { accK[r] = 0.f; accV[r] = 0.f; accQ[r] = 0.f; }

    const int c0 = wv * 128;
    const float* wkp = Wk + (size_t)c0 * DD + lane;
    const float* wvp = Wv + (size_t)c0 * DD + lane;
    const float* wqp = Wq + (size_t)c0 * DD + lane;

    float wkA[8], wlA[8], wkB[8], wlB[8], wq[8];

    LOADKV(wkA, wlA, 0)
    for (int g = 0; g < 16; g += 2) {
        LOADKV(wkB, wlB, g + 1)
        LOADQ(g)
        COMPKV(wkA, wlA, g)
        COMPQ(g)
        const int gn = (g + 2 < 16) ? (g + 2) : 0;   // tail wrap: harmless
        LOADKV(wkA, wlA, gn)
        LOADQ(g + 1)
        COMPKV(wkB, wlB, g + 1)
        COMPQ(g + 1)
    }
    __syncthreads();            // x panel no longer needed -> reuse as red

    // ---- cross-wave reduction: red[4][1536], waves 4-7 add onto 0-3 ----
    float* red = smem;
    const int base = (wv & 3) * 1536;
    if (wv < 4) {
#pragma unroll
        for (int r = 0; r < PR; ++r) {
            red[base + lane * PR + r]        = accK[r];   // k: [d][r]
            red[base + 512 + r * DD + lane]  = accV[r];   // v: [r][d]
        }
        if (needq)
#pragma unroll
            for (int r = 0; r < PR; ++r)
                red[base + 1024 + r * DD + lane] = accQ[r];
    }
    __syncthreads();
    if (wv >= 4) {
#pragma unroll
        for (int r = 0; r < PR; ++r) {
            red[base + lane * PR + r]       += accK[r];
            red[base + 512 + r * DD + lane] += accV[r];
        }
        if (needq)
#pragma unroll
            for (int r = 0; r < PR; ++r)
                red[base + 1024 + r * DD + lane] += accQ[r];
    }
    __syncthreads();

    // ---- final 4-way sum + stores ----
    const int nslots = needq ? 1536 : 1024;
    for (int slot = tid; slot < nslots; slot += 512) {
        const float s = red[slot] + red[slot + 1536] +
                        red[slot + 3072] + red[slot + 4608];
        if (slot < 512) {
            const int dd = slot >> 3, r = slot & 7;
            if (r < nr) kT[(size_t)dd * NROW + bs0 + r] = s;
        } else if (slot < 1024) {
            const int i = slot - 512, r = i >> 6, dd = i & 63;
            if (r < nr) vbuf[(size_t)(bs0 + r) * DD + dd] = s;
        } else {
            const int i = slot - 1024, r = i >> 6, dd = i & 63;
            if (r < nr) {
                const int bs = bs0 + r;
                const int b = bs / SS, ss = bs - b * SS;
                if (ss >= TT - 1)
                    qbuf[((size_t)b * TT + (ss - (TT - 1))) * DD + dd] = s;
            }
        }
    }
}

// ---------------------------------------------------------------------------
// Kernel 2: attention, WT=2 windows/block, 1024 blocks x 256 threads.
// Phase 1: thread owns t in {tid, tid+256} for both windows; bias shared
// across m, overlapping k loads L1-hit. wei stored interleaved [t][m]
// (2-way LDS aliasing is free). Softmax: wave wv -> row wv>>1, half wv&1.
// Phase 2: wave covers 128 t; sliding v register serves both windows.
// ---------------------------------------------------------------------------
__global__ __launch_bounds__(256) void attn_kernel(
    const float* __restrict__ kT,     // [DD][NROW]
    const float* __restrict__ vbuf,   // [NROW][DD]
    const float* __restrict__ qbuf,   // [BB*TT][DD]
    const float* __restrict__ bias,   // [DD][TT]
    float* __restrict__ out)          // [BB*TT][DD]
{
    __shared__ __align__(8) float qsT[DD][2];        // [d][m]
    __shared__ __align__(8) float weiT[TT][2];       // [t][m], logits->weights
    __shared__ float red[8];
    __shared__ float invs[2];
    __shared__ float partial[4][2][DD];

    const int tid  = threadIdx.x;
    const int lane = tid & 63;
    const int wv   = tid >> 6;          // 0..3
    const int blk  = blockIdx.x;        // 0..1023
    const int b    = blk >> 8;          // 256 w-blocks per batch
    const int w0   = (blk & 255) * 2;

    if (tid < 2 * DD) {
        const int m = tid >> 6, dd = tid & 63;
        qsT[dd][m] = qbuf[((size_t)b * TT + w0 + m) * DD + dd];
    }
    __syncthreads();

    // ---- phase 1: logits for t in {tid, tid+256}, m in {0,1} ----
    {
        const float* kcol = kT + (size_t)b * SS + w0;
        float a00 = 0.f, a10 = 0.f, a01 = 0.f, a11 = 0.f;   // a[m][j]
#pragma unroll 4
        for (int dd = 0; dd < DD; ++dd) {
            const float* kr = kcol + (size_t)dd * NROW;
            const float b0 = bias[dd * TT + tid];
            const float b1 = bias[dd * TT + tid + 256];
            const float q0 = qsT[dd][0], q1 = qsT[dd][1];
            const float k0 = kr[tid],       k1 = kr[tid + 1];
            const float k2 = kr[tid + 256], k3 = kr[tid + 257];
            a00 = fmaf(q0, k0 + b0, a00);
            a10 = fmaf(q1, k1 + b0, a10);
            a01 = fmaf(q0, k2 + b1, a01);
            a11 = fmaf(q1, k3 + b1, a11);
        }
        weiT[tid][0]       = a00; weiT[tid][1]       = a10;
        weiT[tid + 256][0] = a01; weiT[tid + 256][1] = a11;
    }
    __syncthreads();

    // ---- softmax: wave wv handles row m = wv>>1, half = wv&1 ----
    {
        const int m = wv >> 1, half = wv & 1;
        const int tb = half * 256 + lane;
        float r0 = weiT[tb][m],       r1 = weiT[tb + 64][m];
        float r2 = weiT[tb + 128][m], r3 = weiT[tb + 192][m];
        float mx = fmaxf(fmaxf(r0, r1), fmaxf(r2, r3));
#pragma unroll
        for (int off = 1; off < 64; off <<= 1)
            mx = fmaxf(mx, __shfl_xor(mx, off, 64));
        if (lane == 0) red[wv] = mx;
        __syncthreads();
        mx = fmaxf(red[m * 2], red[m * 2 + 1]);
        const float e0 = __expf(r0 - mx), e1 = __expf(r1 - mx);
        const float e2 = __expf(r2 - mx), e3 = __expf(r3 - mx);
        weiT[tb][m] = e0;       weiT[tb + 64][m] = e1;
        weiT[tb + 128][m] = e2; weiT[tb + 192][m] = e3;
        float sum = (e0 + e1) + (e2 + e3);
#pragma unroll
        for (int off = 1; off < 64; off <<= 1)
            sum += __shfl_xor(sum, off, 64);
        if (lane == 0) red[4 + wv] = sum;
        __syncthreads();
        if (tid < 2) invs[tid] = 1.f / (red[4 + tid * 2] + red[5 + tid * 2]);
    }
    __syncthreads();

    // ---- phase 2: PV, wave wv covers 128 t, sliding v register ----
    {
        const int t0r = wv * 128;
        const float* vb = vbuf + ((size_t)b * SS + w0 + t0r) * DD + lane;
        float p0 = 0.f, p1 = 0.f;
        float v0 = vb[0];
#pragma unroll 4
        for (int t = 0; t < 128; ++t) {
            const float v1 = vb[(size_t)(t + 1) * DD];
            const f2 w2 = *(const f2*)&weiT[t0r + t][0];
            p0 = fmaf(w2[0], v0, p0);
            p1 = fmaf(w2[1], v1, p1);
            v0 = v1;
        }
        partial[wv][0][lane] = p0;
        partial[wv][1][lane] = p1;
    }
    __syncthreads();

    // ---- final reduce + store ----
    if (tid < 2 * DD) {
        const int m = tid >> 6, dd = tid & 63;
        const float o = (partial[0][m][dd] + partial[1][m][dd] +
                         partial[2][m][dd] + partial[3][m][dd]) * invs[m];
        out[((size_t)b * TT + w0 + m) * DD + dd] = o;
    }
}

// ---------------------------------------------------------------------------
extern "C" void kernel_launch(void* const* d_in, const int* in_sizes, int n_in,
                              void* d_out, int out_size, void* d_ws, size_t ws_size,
                              hipStream_t stream) {
    const float* x    = (const float*)d_in[0];
    const float* Wk   = (const float*)d_in[1];
    const float* Wv   = (const float*)d_in[2];
    const float* Wq   = (const float*)d_in[3];
    const float* bias = (const float*)d_in[4];
    float* out = (float*)d_out;

    float* kT   = (float*)d_ws;                     // DD*NROW
    float* vbuf = kT + (size_t)DD * NROW;           // NROW*DD
    float* qbuf = vbuf + (size_t)NROW * DD;         // BB*TT*DD

    proj_kernel<<<PBLOCKS, 512, 0, stream>>>(x, Wk, Wv, Wq, kT, vbuf, qbuf);
    attn_kernel<<<BB * TT / 2, 256, 0, stream>>>(kT, vbuf, qbuf, bias, out);
}

// Round 9
// 131.583 us; speedup vs baseline: 5.3507x; 5.3507x over previous
//
#include <hip/hip_runtime.h>
#include <hip/hip_bf16.h>

#define BB 4      // batch
#define SS 1023   // source length = 2T-1
#define TT 512    // window length
#define CC 1024   // embed dim
#define DD 64     // head size
#define NROW (BB*SS)    // 4092
#define PR 4            // proj rows per block
#define PBLOCKS (NROW / PR)   // 1023

typedef float f4 __attribute__((ext_vector_type(4)));
typedef float f2 __attribute__((ext_vector_type(2)));

// ---------------------------------------------------------------------------
// Kernel 1: projections k|v|q = x @ [Wk|Wv|Wq].
// 1023 blocks x 512 threads (8184 waves ~ 100% nominal occupancy).
// Block owns PR=4 x-rows staged in 16 KB LDS. Wave wv covers K-slice
// [128wv, 128wv+128); lane = output d. W loads software-pipelined through
// two 4-wide register banks, inline constant-indexed (SROA-safe; round-7
// proven). NOTE: plain __launch_bounds__(512) — the (512,4) variant caps
// VGPR at 64 and spilled to scratch in rounds 6/8.
// k stored transposed kT[d][row] for coalesced attn phase-1.
// ---------------------------------------------------------------------------
__global__ __launch_bounds__(512) void proj_kernel(
    const float* __restrict__ x,
    const float* __restrict__ Wk,
    const float* __restrict__ Wv,
    const float* __restrict__ Wq,
    float* __restrict__ kT,     // [DD][NROW]
    float* __restrict__ vbuf,   // [NROW][DD]
    float* __restrict__ qbuf)   // [BB*TT][DD]
{
    __shared__ __align__(16) float smem[PR * CC];   // 16 KB; later red[4][768]

    const int tid  = threadIdx.x;
    const int lane = tid & 63;
    const int wv   = tid >> 6;              // 0..7
    const int bs0  = blockIdx.x * PR;
    const int s0   = bs0 % SS;
    const bool needq = (s0 + PR - 1) >= (TT - 1);

    // ---- stage x panel: 4 rows x 1024 floats, coalesced f4 ----
    {
        const f4* xg = (const f4*)x;
        f4* xs4 = (f4*)smem;
#pragma unroll
        for (int j = 0; j < 2; ++j) {
            const int idx = tid + j * 512;         // 0..1023
            const int r = idx >> 8, c4 = idx & 255;
            xs4[idx] = xg[(size_t)(bs0 + r) * (CC / 4) + c4];
        }
    }
    __syncthreads();

    float accK[PR], accV[PR], accQ[PR];
#pragma unroll
    for (int r = 0; r < PR; ++r) { accK[r] = 0.f; accV[r] = 0.f; accQ[r] = 0.f; }

    const int c0 = wv * 128;
    const float* wkp = Wk + (size_t)c0 * DD + lane;
    const float* wvp = Wv + (size_t)c0 * DD + lane;
    const float* wqp = Wq + (size_t)c0 * DD + lane;

    float wkA[4], wlA[4], wqA[4], wkB[4], wlB[4], wqB[4];

    // preload bank A for c4 = 0
#pragma unroll
    for (int kk = 0; kk < 4; ++kk) {
        wkA[kk] = wkp[kk * DD];
        wlA[kk] = wvp[kk * DD];
    }
    if (needq) {
#pragma unroll
        for (int kk = 0; kk < 4; ++kk) wqA[kk] = wqp[kk * DD];
    }

    for (int c4 = 0; c4 < 32; c4 += 2) {
        // ---- prefetch bank B (c4+1) ----
#pragma unroll
        for (int kk = 0; kk < 4; ++kk) {
            const int cl = (c4 + 1) * 4 + kk;
            wkB[kk] = wkp[cl * DD];
            wlB[kk] = wvp[cl * DD];
        }
        if (needq) {
#pragma unroll
            for (int kk = 0; kk < 4; ++kk)
                wqB[kk] = wqp[((c4 + 1) * 4 + kk) * DD];
        }
        // ---- compute with bank A (c4) ----
        {
            f4 xv[PR];
#pragma unroll
            for (int r = 0; r < PR; ++r)
                xv[r] = *(const f4*)&smem[r * CC + c0 + c4 * 4];
#pragma unroll
            for (int kk = 0; kk < 4; ++kk)
#pragma unroll
                for (int r = 0; r < PR; ++r) {
                    accK[r] = fmaf(xv[r][kk], wkA[kk], accK[r]);
                    accV[r] = fmaf(xv[r][kk], wlA[kk], accV[r]);
                }
            if (needq) {
#pragma unroll
                for (int kk = 0; kk < 4; ++kk)
#pragma unroll
                    for (int r = 0; r < PR; ++r)
                        accQ[r] = fmaf(xv[r][kk], wqA[kk], accQ[r]);
            }
        }
        // ---- prefetch bank A (c4+2); tail wraps to 0 (harmless reload) ----
        {
            const int c4n = (c4 + 2 < 32) ? (c4 + 2) : 0;
#pragma unroll
            for (int kk = 0; kk < 4; ++kk) {
                const int cl = c4n * 4 + kk;
                wkA[kk] = wkp[cl * DD];
                wlA[kk] = wvp[cl * DD];
            }
            if (needq) {
#pragma unroll
                for (int kk = 0; kk < 4; ++kk)
                    wqA[kk] = wqp[(c4n * 4 + kk) * DD];
            }
        }
        // ---- compute with bank B (c4+1) ----
        {
            f4 xv[PR];
#pragma unroll
            for (int r = 0; r < PR; ++r)
                xv[r] = *(const f4*)&smem[r * CC + c0 + (c4 + 1) * 4];
#pragma unroll
            for (int kk = 0; kk < 4; ++kk)
#pragma unroll
                for (int r = 0; r < PR; ++r) {
                    accK[r] = fmaf(xv[r][kk], wkB[kk], accK[r]);
                    accV[r] = fmaf(xv[r][kk], wlB[kk], accV[r]);
                }
            if (needq) {
#pragma unroll
                for (int kk = 0; kk < 4; ++kk)
#pragma unroll
                    for (int r = 0; r < PR; ++r)
                        accQ[r] = fmaf(xv[r][kk], wqB[kk], accQ[r]);
            }
        }
    }
    __syncthreads();            // x panel no longer needed -> reuse as red

    // ---- cross-wave reduction: red[4][768], waves 4-7 add onto 0-3 ----
    float* red = smem;
    const int base = (wv & 3) * 768;
    if (wv < 4) {
#pragma unroll
        for (int r = 0; r < PR; ++r) {
            red[base + lane * PR + r]        = accK[r];   // k: [d][r]
            red[base + 256 + r * DD + lane]  = accV[r];   // v: [r][d]
        }
        if (needq)
#pragma unroll
            for (int r = 0; r < PR; ++r)
                red[base + 512 + r * DD + lane] = accQ[r];
    }
    __syncthreads();
    if (wv >= 4) {
#pragma unroll
        for (int r = 0; r < PR; ++r) {
            red[base + lane * PR + r]       += accK[r];
            red[base + 256 + r * DD + lane] += accV[r];
        }
        if (needq)
#pragma unroll
            for (int r = 0; r < PR; ++r)
                red[base + 512 + r * DD + lane] += accQ[r];
    }
    __syncthreads();

    // ---- final 4-way sum + stores ----
    const int nslots = needq ? 768 : 512;
    for (int slot = tid; slot < nslots; slot += 512) {
        const float s = red[slot] + red[slot + 768] +
                        red[slot + 1536] + red[slot + 2304];
        if (slot < 256) {
            const int dd = slot >> 2, r = slot & 3;
            kT[(size_t)dd * NROW + bs0 + r] = s;
        } else if (slot < 512) {
            const int i = slot - 256, r = i >> 6, dd = i & 63;
            vbuf[(size_t)(bs0 + r) * DD + dd] = s;
        } else {
            const int i = slot - 512, r = i >> 6, dd = i & 63;
            const int bs = bs0 + r;
            const int b = bs / SS, ss = bs - b * SS;
            if (ss >= TT - 1)
                qbuf[((size_t)b * TT + (ss - (TT - 1))) * DD + dd] = s;
        }
    }
}

// ---------------------------------------------------------------------------
// Kernel 2: attention, WT=2 windows/block, 1024 blocks x 512 threads
// (8192 waves ~ 100% nominal occupancy).
// Phase 1: thread owns t = tid for both windows (bias shared, k overlap L1).
// Softmax: wave wv -> row m = wv>>2, quarter wv&3 (128 t each).
// Phase 2: wave wv covers 64 t; sliding v register serves both windows.
// ---------------------------------------------------------------------------
__global__ __launch_bounds__(512) void attn_kernel(
    const float* __restrict__ kT,     // [DD][NROW]
    const float* __restrict__ vbuf,   // [NROW][DD]
    const float* __restrict__ qbuf,   // [BB*TT][DD]
    const float* __restrict__ bias,   // [DD][TT]
    float* __restrict__ out)          // [BB*TT][DD]
{
    __shared__ __align__(8) float qsT[DD][2];        // [d][m]
    __shared__ __align__(8) float weiT[TT][2];       // [t][m], logits->weights
    __shared__ float red[16];
    __shared__ float invs[2];
    __shared__ float partial[8][2][DD];              // 4 KB

    const int tid  = threadIdx.x;
    const int lane = tid & 63;
    const int wv   = tid >> 6;          // 0..7
    const int blk  = blockIdx.x;        // 0..1023
    const int b    = blk >> 8;          // 256 w-blocks per batch
    const int w0   = (blk & 255) * 2;

    if (tid < 2 * DD) {
        const int m = tid >> 6, dd = tid & 63;
        qsT[dd][m] = qbuf[((size_t)b * TT + w0 + m) * DD + dd];
    }
    __syncthreads();

    // ---- phase 1: logits for t = tid, m in {0,1} ----
    {
        const int t = tid;
        const float* kcol = kT + (size_t)b * SS + w0 + t;
        float a0 = 0.f, a1 = 0.f;
#pragma unroll 4
        for (int dd = 0; dd < DD; ++dd) {
            const float* kr = kcol + (size_t)dd * NROW;
            const float b0 = bias[dd * TT + t];
            const float q0 = qsT[dd][0], q1 = qsT[dd][1];
            const float k0 = kr[0], k1 = kr[1];
            a0 = fmaf(q0, k0 + b0, a0);
            a1 = fmaf(q1, k1 + b0, a1);
        }
        weiT[t][0] = a0;
        weiT[t][1] = a1;
    }
    __syncthreads();

    // ---- softmax: wave wv -> row m = wv>>2, quarter qt = wv&3 ----
    {
        const int m = wv >> 2, qt = wv & 3;
        const int tb = qt * 128 + lane;
        float r0 = weiT[tb][m], r1 = weiT[tb + 64][m];
        float mx = fmaxf(r0, r1);
#pragma unroll
        for (int off = 1; off < 64; off <<= 1)
            mx = fmaxf(mx, __shfl_xor(mx, off, 64));
        if (lane == 0) red[wv] = mx;
        __syncthreads();
        mx = fmaxf(fmaxf(red[m * 4], red[m * 4 + 1]),
                   fmaxf(red[m * 4 + 2], red[m * 4 + 3]));
        const float e0 = __expf(r0 - mx), e1 = __expf(r1 - mx);
        weiT[tb][m] = e0;
        weiT[tb + 64][m] = e1;
        float sum = e0 + e1;
#pragma unroll
        for (int off = 1; off < 64; off <<= 1)
            sum += __shfl_xor(sum, off, 64);
        if (lane == 0) red[8 + wv] = sum;
        __syncthreads();
        if (tid < 2)
            invs[tid] = 1.f / (red[8 + tid * 4] + red[9 + tid * 4] +
                               red[10 + tid * 4] + red[11 + tid * 4]);
    }
    __syncthreads();

    // ---- phase 2: PV, wave wv covers 64 t, sliding v register ----
    {
        const int t0r = wv * 64;
        const float* vb = vbuf + ((size_t)b * SS + w0 + t0r) * DD + lane;
        float p0 = 0.f, p1 = 0.f;
        float v0 = vb[0];
#pragma unroll 4
        for (int t = 0; t < 64; ++t) {
            const float v1 = vb[(size_t)(t + 1) * DD];
            const f2 w2 = *(const f2*)&weiT[t0r + t][0];
            p0 = fmaf(w2[0], v0, p0);
            p1 = fmaf(w2[1], v1, p1);
            v0 = v1;
        }
        partial[wv][0][lane] = p0;
        partial[wv][1][lane] = p1;
    }
    __syncthreads();

    // ---- final reduce + store ----
    if (tid < 2 * DD) {
        const int m = tid >> 6, dd = tid & 63;
        float o = 0.f;
#pragma unroll
        for (int j = 0; j < 8; ++j) o += partial[j][m][dd];
        out[((size_t)b * TT + w0 + m) * DD + dd] = o * invs[m];
    }
}

// ---------------------------------------------------------------------------
extern "C" void kernel_launch(void* const* d_in, const int* in_sizes, int n_in,
                              void* d_out, int out_size, void* d_ws, size_t ws_size,
                              hipStream_t stream) {
    const float* x    = (const float*)d_in[0];
    const float* Wk   = (const float*)d_in[1];
    const float* Wv   = (const float*)d_in[2];
    const float* Wq   = (const float*)d_in[3];
    const float* bias = (const float*)d_in[4];
    float* out = (float*)d_out;

    float* kT   = (float*)d_ws;                     // DD*NROW
    float* vbuf = kT + (size_t)DD * NROW;           // NROW*DD
    float* qbuf = vbuf + (size_t)NROW * DD;         // BB*TT*DD

    proj_kernel<<<PBLOCKS, 512, 0, stream>>>(x, Wk, Wv, Wq, kT, vbuf, qbuf);
    attn_kernel<<<BB * TT / 2, 512, 0, stream>>>(kT, vbuf, qbuf, bias, out);
}

// Round 10
// 131.573 us; speedup vs baseline: 5.3511x; 1.0001x over previous
//
#include <hip/hip_runtime.h>
#include <hip/hip_bf16.h>

#define BB 4      // batch
#define SS 1023   // source length = 2T-1
#define TT 512    // window length
#define CC 1024   // embed dim
#define DD 64     // head size
#define NROW (BB*SS)    // 4092
#define PR 4            // proj rows per block
#define PBLOCKS (NROW / PR)   // 1023

typedef float f4 __attribute__((ext_vector_type(4)));
typedef float f2 __attribute__((ext_vector_type(2)));

// ---------------------------------------------------------------------------
// Kernel 1: projections k|v|q = x @ [Wk|Wv|Wq].  (round-9 proven version)
// 1023 blocks x 512 threads. PR=4 x-rows in 16 KB LDS; wave wv covers
// K-slice [128wv,128wv+128); lane = output d; inline A/B register banks.
// NOTE: plain __launch_bounds__(512) — (512,4) caps VGPR at 64 and spills.
// ---------------------------------------------------------------------------
__global__ __launch_bounds__(512) void proj_kernel(
    const float* __restrict__ x,
    const float* __restrict__ Wk,
    const float* __restrict__ Wv,
    const float* __restrict__ Wq,
    float* __restrict__ kT,     // [DD][NROW]
    float* __restrict__ vbuf,   // [NROW][DD]
    float* __restrict__ qbuf)   // [BB*TT][DD]
{
    __shared__ __align__(16) float smem[PR * CC];   // 16 KB; later red[4][768]

    const int tid  = threadIdx.x;
    const int lane = tid & 63;
    const int wv   = tid >> 6;              // 0..7
    const int bs0  = blockIdx.x * PR;
    const int s0   = bs0 % SS;
    const bool needq = (s0 + PR - 1) >= (TT - 1);

    {
        const f4* xg = (const f4*)x;
        f4* xs4 = (f4*)smem;
#pragma unroll
        for (int j = 0; j < 2; ++j) {
            const int idx = tid + j * 512;         // 0..1023
            const int r = idx >> 8, c4 = idx & 255;
            xs4[idx] = xg[(size_t)(bs0 + r) * (CC / 4) + c4];
        }
    }
    __syncthreads();

    float accK[PR], accV[PR], accQ[PR];
#pragma unroll
    for (int r = 0; r < PR; ++r) { accK[r] = 0.f; accV[r] = 0.f; accQ[r] = 0.f; }

    const int c0 = wv * 128;
    const float* wkp = Wk + (size_t)c0 * DD + lane;
    const float* wvp = Wv + (size_t)c0 * DD + lane;
    const float* wqp = Wq + (size_t)c0 * DD + lane;

    float wkA[4], wlA[4], wqA[4], wkB[4], wlB[4], wqB[4];

#pragma unroll
    for (int kk = 0; kk < 4; ++kk) {
        wkA[kk] = wkp[kk * DD];
        wlA[kk] = wvp[kk * DD];
    }
    if (needq) {
#pragma unroll
        for (int kk = 0; kk < 4; ++kk) wqA[kk] = wqp[kk * DD];
    }

    for (int c4 = 0; c4 < 32; c4 += 2) {
#pragma unroll
        for (int kk = 0; kk < 4; ++kk) {
            const int cl = (c4 + 1) * 4 + kk;
            wkB[kk] = wkp[cl * DD];
            wlB[kk] = wvp[cl * DD];
        }
        if (needq) {
#pragma unroll
            for (int kk = 0; kk < 4; ++kk)
                wqB[kk] = wqp[((c4 + 1) * 4 + kk) * DD];
        }
        {
            f4 xv[PR];
#pragma unroll
            for (int r = 0; r < PR; ++r)
                xv[r] = *(const f4*)&smem[r * CC + c0 + c4 * 4];
#pragma unroll
            for (int kk = 0; kk < 4; ++kk)
#pragma unroll
                for (int r = 0; r < PR; ++r) {
                    accK[r] = fmaf(xv[r][kk], wkA[kk], accK[r]);
                    accV[r] = fmaf(xv[r][kk], wlA[kk], accV[r]);
                }
            if (needq) {
#pragma unroll
                for (int kk = 0; kk < 4; ++kk)
#pragma unroll
                    for (int r = 0; r < PR; ++r)
                        accQ[r] = fmaf(xv[r][kk], wqA[kk], accQ[r]);
            }
        }
        {
            const int c4n = (c4 + 2 < 32) ? (c4 + 2) : 0;
#pragma unroll
            for (int kk = 0; kk < 4; ++kk) {
                const int cl = c4n * 4 + kk;
                wkA[kk] = wkp[cl * DD];
                wlA[kk] = wvp[cl * DD];
            }
            if (needq) {
#pragma unroll
                for (int kk = 0; kk < 4; ++kk)
                    wqA[kk] = wqp[(c4n * 4 + kk) * DD];
            }
        }
        {
            f4 xv[PR];
#pragma unroll
            for (int r = 0; r < PR; ++r)
                xv[r] = *(const f4*)&smem[r * CC + c0 + (c4 + 1) * 4];
#pragma unroll
            for (int kk = 0; kk < 4; ++kk)
#pragma unroll
                for (int r = 0; r < PR; ++r) {
                    accK[r] = fmaf(xv[r][kk], wkB[kk], accK[r]);
                    accV[r] = fmaf(xv[r][kk], wlB[kk], accV[r]);
                }
            if (needq) {
#pragma unroll
                for (int kk = 0; kk < 4; ++kk)
#pragma unroll
                    for (int r = 0; r < PR; ++r)
                        accQ[r] = fmaf(xv[r][kk], wqB[kk], accQ[r]);
            }
        }
    }
    __syncthreads();

    float* red = smem;
    const int base = (wv & 3) * 768;
    if (wv < 4) {
#pragma unroll
        for (int r = 0; r < PR; ++r) {
            red[base + lane * PR + r]        = accK[r];
            red[base + 256 + r * DD + lane]  = accV[r];
        }
        if (needq)
#pragma unroll
            for (int r = 0; r < PR; ++r)
                red[base + 512 + r * DD + lane] = accQ[r];
    }
    __syncthreads();
    if (wv >= 4) {
#pragma unroll
        for (int r = 0; r < PR; ++r) {
            red[base + lane * PR + r]       += accK[r];
            red[base + 256 + r * DD + lane] += accV[r];
        }
        if (needq)
#pragma unroll
            for (int r = 0; r < PR; ++r)
                red[base + 512 + r * DD + lane] += accQ[r];
    }
    __syncthreads();

    const int nslots = needq ? 768 : 512;
    for (int slot = tid; slot < nslots; slot += 512) {
        const float s = red[slot] + red[slot + 768] +
                        red[slot + 1536] + red[slot + 2304];
        if (slot < 256) {
            const int dd = slot >> 2, r = slot & 3;
            kT[(size_t)dd * NROW + bs0 + r] = s;
        } else if (slot < 512) {
            const int i = slot - 256, r = i >> 6, dd = i & 63;
            vbuf[(size_t)(bs0 + r) * DD + dd] = s;
        } else {
            const int i = slot - 512, r = i >> 6, dd = i & 63;
            const int bs = bs0 + r;
            const int b = bs / SS, ss = bs - b * SS;
            if (ss >= TT - 1)
                qbuf[((size_t)b * TT + (ss - (TT - 1))) * DD + dd] = s;
        }
    }
}

// ---------------------------------------------------------------------------
// Kernel 2: qb[b,w,t] = sum_d q[b,w,d] * bias[d,t]  (separable bias term).
// 512 blocks x 512 threads; block = 4 windows, thread = one t.
// bias read once per block (128 KB -> 67 MB total vs 134 MB when fused).
// ---------------------------------------------------------------------------
__global__ __launch_bounds__(512) void qbias_kernel(
    const float* __restrict__ qbuf,   // [BB*TT][DD]
    const float* __restrict__ bias,   // [DD][TT]
    float* __restrict__ qb)           // [BB*TT][TT]
{
    __shared__ __align__(16) float qsT[DD][4];   // [d][m]

    const int tid = threadIdx.x;
    const int blk = blockIdx.x;            // 0..511
    const int b   = blk >> 7;              // 128 w-groups per batch
    const int w0  = (blk & 127) * 4;

    if (tid < 4 * DD) {
        const int m = tid >> 6, dd = tid & 63;
        qsT[dd][m] = qbuf[((size_t)b * TT + w0 + m) * DD + dd];
    }
    __syncthreads();

    const int t = tid;
    f4 acc = {0.f, 0.f, 0.f, 0.f};
#pragma unroll 8
    for (int dd = 0; dd < DD; ++dd) {
        const float bb = bias[dd * TT + t];
        const f4 qv = *(const f4*)&qsT[dd][0];
        acc[0] = fmaf(qv[0], bb, acc[0]);
        acc[1] = fmaf(qv[1], bb, acc[1]);
        acc[2] = fmaf(qv[2], bb, acc[2]);
        acc[3] = fmaf(qv[3], bb, acc[3]);
    }
#pragma unroll
    for (int m = 0; m < 4; ++m)
        qb[((size_t)b * TT + w0 + m) * TT + t] = acc[m];
}

// ---------------------------------------------------------------------------
// Kernel 3: attention, WT=2 windows/block, 1024 blocks x 512 threads.
// Phase 1: acc seeded from qb (bias term precomputed) -> pure 2-load/2-FMA
// per dd. Softmax: wave wv -> row m = wv>>2, quarter wv&3.
// Phase 2: wave wv covers 64 t; sliding v register serves both windows.
// ---------------------------------------------------------------------------
__global__ __launch_bounds__(512) void attn_kernel(
    const float* __restrict__ kT,     // [DD][NROW]
    const float* __restrict__ vbuf,   // [NROW][DD]
    const float* __restrict__ qbuf,   // [BB*TT][DD]
    const float* __restrict__ qb,     // [BB*TT][TT]
    float* __restrict__ out)          // [BB*TT][DD]
{
    __shared__ __align__(8) float qsT[DD][2];        // [d][m]
    __shared__ __align__(8) float weiT[TT][2];       // [t][m]
    __shared__ float red[16];
    __shared__ float invs[2];
    __shared__ float partial[8][2][DD];

    const int tid  = threadIdx.x;
    const int lane = tid & 63;
    const int wv   = tid >> 6;          // 0..7
    const int blk  = blockIdx.x;        // 0..1023
    const int b    = blk >> 8;          // 256 w-blocks per batch
    const int w0   = (blk & 255) * 2;

    if (tid < 2 * DD) {
        const int m = tid >> 6, dd = tid & 63;
        qsT[dd][m] = qbuf[((size_t)b * TT + w0 + m) * DD + dd];
    }
    __syncthreads();

    // ---- phase 1: logits for t = tid, m in {0,1} ----
    {
        const int t = tid;
        const float* kcol = kT + (size_t)b * SS + w0 + t;
        const float* qbp  = qb + ((size_t)b * TT + w0) * TT + t;
        float a0 = qbp[0];
        float a1 = qbp[TT];
#pragma unroll 8
        for (int dd = 0; dd < DD; ++dd) {
            const float* kr = kcol + (size_t)dd * NROW;
            const float q0 = qsT[dd][0], q1 = qsT[dd][1];
            a0 = fmaf(q0, kr[0], a0);
            a1 = fmaf(q1, kr[1], a1);
        }
        weiT[t][0] = a0;
        weiT[t][1] = a1;
    }
    __syncthreads();

    // ---- softmax: wave wv -> row m = wv>>2, quarter qt = wv&3 ----
    {
        const int m = wv >> 2, qt = wv & 3;
        const int tb = qt * 128 + lane;
        float r0 = weiT[tb][m], r1 = weiT[tb + 64][m];
        float mx = fmaxf(r0, r1);
#pragma unroll
        for (int off = 1; off < 64; off <<= 1)
            mx = fmaxf(mx, __shfl_xor(mx, off, 64));
        if (lane == 0) red[wv] = mx;
        __syncthreads();
        mx = fmaxf(fmaxf(red[m * 4], red[m * 4 + 1]),
                   fmaxf(red[m * 4 + 2], red[m * 4 + 3]));
        const float e0 = __expf(r0 - mx), e1 = __expf(r1 - mx);
        weiT[tb][m] = e0;
        weiT[tb + 64][m] = e1;
        float sum = e0 + e1;
#pragma unroll
        for (int off = 1; off < 64; off <<= 1)
            sum += __shfl_xor(sum, off, 64);
        if (lane == 0) red[8 + wv] = sum;
        __syncthreads();
        if (tid < 2)
            invs[tid] = 1.f / (red[8 + tid * 4] + red[9 + tid * 4] +
                               red[10 + tid * 4] + red[11 + tid * 4]);
    }
    __syncthreads();

    // ---- phase 2: PV, wave wv covers 64 t, sliding v register ----
    {
        const int t0r = wv * 64;
        const float* vb = vbuf + ((size_t)b * SS + w0 + t0r) * DD + lane;
        float p0 = 0.f, p1 = 0.f;
        float v0 = vb[0];
#pragma unroll 4
        for (int t = 0; t < 64; ++t) {
            const float v1 = vb[(size_t)(t + 1) * DD];
            const f2 w2 = *(const f2*)&weiT[t0r + t][0];
            p0 = fmaf(w2[0], v0, p0);
            p1 = fmaf(w2[1], v1, p1);
            v0 = v1;
        }
        partial[wv][0][lane] = p0;
        partial[wv][1][lane] = p1;
    }
    __syncthreads();

    // ---- final reduce + store ----
    if (tid < 2 * DD) {
        const int m = tid >> 6, dd = tid & 63;
        float o = 0.f;
#pragma unroll
        for (int j = 0; j < 8; ++j) o += partial[j][m][dd];
        out[((size_t)b * TT + w0 + m) * DD + dd] = o * invs[m];
    }
}

// ---------------------------------------------------------------------------
extern "C" void kernel_launch(void* const* d_in, const int* in_sizes, int n_in,
                              void* d_out, int out_size, void* d_ws, size_t ws_size,
                              hipStream_t stream) {
    const float* x    = (const float*)d_in[0];
    const float* Wk   = (const float*)d_in[1];
    const float* Wv   = (const float*)d_in[2];
    const float* Wq   = (const float*)d_in[3];
    const float* bias = (const float*)d_in[4];
    float* out = (float*)d_out;

    float* kT   = (float*)d_ws;                     // DD*NROW
    float* vbuf = kT + (size_t)DD * NROW;           // NROW*DD
    float* qbuf = vbuf + (size_t)NROW * DD;         // BB*TT*DD
    float* qb   = qbuf + (size_t)BB * TT * DD;      // BB*TT*TT (4 MB)

    proj_kernel<<<PBLOCKS, 512, 0, stream>>>(x, Wk, Wv, Wq, kT, vbuf, qbuf);
    qbias_kernel<<<BB * TT / 4, 512, 0, stream>>>(qbuf, bias, qb);
    attn_kernel<<<BB * TT / 2, 512, 0, stream>>>(kT, vbuf, qbuf, qb, out);
}

// Round 12
// 126.043 us; speedup vs baseline: 5.5859x; 1.0439x over previous
//
#include <hip/hip_runtime.h>
#include <hip/hip_bf16.h>

#define BB 4      // batch
#define SS 1023   // source length = 2T-1
#define TT 512    // window length
#define CC 1024   // embed dim
#define DD 64     // head size
#define NROW (BB*SS)    // 4092

typedef float f4 __attribute__((ext_vector_type(4)));
typedef float f2 __attribute__((ext_vector_type(2)));
typedef short bf16x8 __attribute__((ext_vector_type(8)));
typedef float f32x4 __attribute__((ext_vector_type(4)));
typedef unsigned short us4 __attribute__((ext_vector_type(4)));

// round-to-nearest-even bf16 split: v ~= hi + lo, both bf16 (packed u32 lo<<16|hi)
__device__ __forceinline__ unsigned split_rtn(float v) {
    const unsigned u  = __builtin_bit_cast(unsigned, v);
    const unsigned r  = u + 0x7FFFu + ((u >> 16) & 1u);
    const unsigned hi = r >> 16;
    const float hif   = __builtin_bit_cast(float, r & 0xFFFF0000u);
    const float res   = v - hif;                       // exact (Sterbenz)
    const unsigned u2 = __builtin_bit_cast(unsigned, res);
    const unsigned r2 = u2 + 0x7FFFu + ((u2 >> 16) & 1u);
    return (r2 & 0xFFFF0000u) | hi;                    // lo<<16 | hi
}

// ---------------------------------------------------------------------------
// Kernel 1: split x (fp32) into bf16 hi/lo planes (RTN), row-major [NROW][CC].
// ---------------------------------------------------------------------------
__global__ __launch_bounds__(512) void xsplit_kernel(
    const float* __restrict__ x,
    unsigned short* __restrict__ xh,
    unsigned short* __restrict__ xl)
{
    const int idx = blockIdx.x * 512 + threadIdx.x;
    const f4 v = ((const f4*)x)[idx];
    us4 h, l;
#pragma unroll
    for (int j = 0; j < 4; ++j) {
        const unsigned hl = split_rtn(v[j]);
        h[j] = (unsigned short)(hl & 0xFFFFu);
        l[j] = (unsigned short)(hl >> 16);
    }
    ((us4*)xh)[idx] = h;
    ((us4*)xl)[idx] = l;
}

// ---------------------------------------------------------------------------
// Kernel 2: split W{k,v,q} into B-fragment-ordered bf16 hi/lo (RTN).
// Frag f = (p*4 + nsub)*32 + ks. Lane holds B[k=ks*32+(lane>>4)*8+j]
// [n=nsub*16+(lane&15)], j=0..7: bw[f*512 + lane*8 + j].
// ---------------------------------------------------------------------------
__global__ __launch_bounds__(64) void wsplit_kernel(
    const float* __restrict__ Wk,
    const float* __restrict__ Wv,
    const float* __restrict__ Wq,
    unsigned short* __restrict__ bwh,
    unsigned short* __restrict__ bwl)
{
    const int f    = blockIdx.x;        // 0..383
    const int p    = f >> 7;
    const int rem  = f & 127;
    const int nsub = rem >> 5;
    const int ks   = rem & 31;
    const int lane = threadIdx.x;
    const int quad = lane >> 4, l4 = lane & 15;
    const float* W = (p == 0) ? Wk : (p == 1) ? Wv : Wq;
    const int n = nsub * 16 + l4;

    bf16x8 h, l;
#pragma unroll
    for (int j = 0; j < 8; ++j) {
        const int k = ks * 32 + quad * 8 + j;
        const unsigned hl = split_rtn(W[k * DD + n]);
        h[j] = (short)(hl & 0xFFFFu);
        l[j] = (short)(hl >> 16);
    }
    ((bf16x8*)bwh)[f * 64 + lane] = h;
    ((bf16x8*)bwl)[f * 64 + lane] = l;
}

// ---------------------------------------------------------------------------
// Kernel 3: projections via MFMA 16x16x32 bf16, full split product
// (ah*bh + ah*bl + al*bh + al*bl = 16 MFMAs / K-step).
// 768 single-wave blocks: blk -> (p = blk%3, M-tile mt = blk/3).
// A-frag: lane holds x[bs0+(lane&15)][ks*32+(lane>>4)*8+j] (one 16B load
// per plane). B-frags: coalesced 16B loads from wsplit output.
// C/D layout (verified): row = (lane>>4)*4 + reg, col = lane&15.
// ---------------------------------------------------------------------------
__global__ __launch_bounds__(64) void proj_mfma_kernel(
    const unsigned short* __restrict__ xh,
    const unsigned short* __restrict__ xl,
    const unsigned short* __restrict__ bwh,
    const unsigned short* __restrict__ bwl,
    float* __restrict__ kT,     // [DD][NROW]
    float* __restrict__ vbuf,   // [NROW][DD]
    float* __restrict__ qbuf)   // [BB*TT][DD]
{
    const int blk  = blockIdx.x;        // 0..767
    const int p    = blk % 3;
    const int mt   = blk / 3;           // 0..255
    const int bs0  = mt * 16;
    const int lane = threadIdx.x;
    const int quad = lane >> 4, l4 = lane & 15;

    int arow = bs0 + l4; if (arow > NROW - 1) arow = NROW - 1;   // pad clamp
    const unsigned short* ahp = xh + (size_t)arow * CC;
    const unsigned short* alp = xl + (size_t)arow * CC;
    const bf16x8* bh = (const bf16x8*)bwh + (size_t)(p * 128) * 64 + lane;
    const bf16x8* bl = (const bf16x8*)bwl + (size_t)(p * 128) * 64 + lane;

    f32x4 acc0 = {0.f,0.f,0.f,0.f}, acc1 = {0.f,0.f,0.f,0.f};
    f32x4 acc2 = {0.f,0.f,0.f,0.f}, acc3 = {0.f,0.f,0.f,0.f};

#pragma unroll 4
    for (int ks = 0; ks < 32; ++ks) {
        const int k0 = ks * 32 + quad * 8;
        const bf16x8 ah = *(const bf16x8*)(ahp + k0);
        const bf16x8 al = *(const bf16x8*)(alp + k0);
        const bf16x8 bh0 = bh[(0 * 32 + ks) * 64];
        const bf16x8 bh1 = bh[(1 * 32 + ks) * 64];
        const bf16x8 bh2 = bh[(2 * 32 + ks) * 64];
        const bf16x8 bh3 = bh[(3 * 32 + ks) * 64];
        const bf16x8 bl0 = bl[(0 * 32 + ks) * 64];
        const bf16x8 bl1 = bl[(1 * 32 + ks) * 64];
        const bf16x8 bl2 = bl[(2 * 32 + ks) * 64];
        const bf16x8 bl3 = bl[(3 * 32 + ks) * 64];

        acc0 = __builtin_amdgcn_mfma_f32_16x16x32_bf16(ah, bh0, acc0, 0, 0, 0);
        acc1 = __builtin_amdgcn_mfma_f32_16x16x32_bf16(ah, bh1, acc1, 0, 0, 0);
        acc2 = __builtin_amdgcn_mfma_f32_16x16x32_bf16(ah, bh2, acc2, 0, 0, 0);
        acc3 = __builtin_amdgcn_mfma_f32_16x16x32_bf16(ah, bh3, acc3, 0, 0, 0);
        acc0 = __builtin_amdgcn_mfma_f32_16x16x32_bf16(ah, bl0, acc0, 0, 0, 0);
        acc1 = __builtin_amdgcn_mfma_f32_16x16x32_bf16(ah, bl1, acc1, 0, 0, 0);
        acc2 = __builtin_amdgcn_mfma_f32_16x16x32_bf16(ah, bl2, acc2, 0, 0, 0);
        acc3 = __builtin_amdgcn_mfma_f32_16x16x32_bf16(ah, bl3, acc3, 0, 0, 0);
        acc0 = __builtin_amdgcn_mfma_f32_16x16x32_bf16(al, bh0, acc0, 0, 0, 0);
        acc1 = __builtin_amdgcn_mfma_f32_16x16x32_bf16(al, bh1, acc1, 0, 0, 0);
        acc2 = __builtin_amdgcn_mfma_f32_16x16x32_bf16(al, bh2, acc2, 0, 0, 0);
        acc3 = __builtin_amdgcn_mfma_f32_16x16x32_bf16(al, bh3, acc3, 0, 0, 0);
        acc0 = __builtin_amdgcn_mfma_f32_16x16x32_bf16(al, bl0, acc0, 0, 0, 0);
        acc1 = __builtin_amdgcn_mfma_f32_16x16x32_bf16(al, bl1, acc1, 0, 0, 0);
        acc2 = __builtin_amdgcn_mfma_f32_16x16x32_bf16(al, bl2, acc2, 0, 0, 0);
        acc3 = __builtin_amdgcn_mfma_f32_16x16x32_bf16(al, bl3, acc3, 0, 0, 0);
    }

    // ---- epilogue: D[row=quad*4+reg][col=l4], d = nsub*16 + l4 ----
#pragma unroll
    for (int nsub = 0; nsub < 4; ++nsub) {
        const f32x4 a = (nsub == 0) ? acc0 : (nsub == 1) ? acc1
                       : (nsub == 2) ? acc2 : acc3;
        const int d = nsub * 16 + l4;
#pragma unroll
        for (int reg = 0; reg < 4; ++reg) {
            const int bs = bs0 + quad * 4 + reg;
            if (bs < NROW) {
                const float val = a[reg];
                if (p == 0) {
                    kT[(size_t)d * NROW + bs] = val;
                } else if (p == 1) {
                    vbuf[(size_t)bs * DD + d] = val;
                } else {
                    const int b = bs / SS, s = bs - b * SS;
                    if (s >= TT - 1)
                        qbuf[((size_t)b * TT + (s - (TT - 1))) * DD + d] = val;
                }
            }
        }
    }
}

// ---------------------------------------------------------------------------
// Kernel 4: qb[b,w,t] = sum_d q[b,w,d] * bias[d,t]  (round-10 proven).
// ---------------------------------------------------------------------------
__global__ __launch_bounds__(512) void qbias_kernel(
    const float* __restrict__ qbuf,   // [BB*TT][DD]
    const float* __restrict__ bias,   // [DD][TT]
    float* __restrict__ qb)           // [BB*TT][TT]
{
    __shared__ __align__(16) float qsT[DD][4];   // [d][m]

    const int tid = threadIdx.x;
    const int blk = blockIdx.x;            // 0..511
    const int b   = blk >> 7;
    const int w0  = (blk & 127) * 4;

    if (tid < 4 * DD) {
        const int m = tid >> 6, dd = tid & 63;
        qsT[dd][m] = qbuf[((size_t)b * TT + w0 + m) * DD + dd];
    }
    __syncthreads();

    const int t = tid;
    f4 acc = {0.f, 0.f, 0.f, 0.f};
#pragma unroll 8
    for (int dd = 0; dd < DD; ++dd) {
        const float bb = bias[dd * TT + t];
        const f4 qv = *(const f4*)&qsT[dd][0];
        acc[0] = fmaf(qv[0], bb, acc[0]);
        acc[1] = fmaf(qv[1], bb, acc[1]);
        acc[2] = fmaf(qv[2], bb, acc[2]);
        acc[3] = fmaf(qv[3], bb, acc[3]);
    }
#pragma unroll
    for (int m = 0; m < 4; ++m)
        qb[((size_t)b * TT + w0 + m) * TT + t] = acc[m];
}

// ---------------------------------------------------------------------------
// Kernel 5: attention, WT=2 windows/block, 1024 blocks x 512 threads
// (round-10 proven version, qb-seeded logits).
// ---------------------------------------------------------------------------
__global__ __launch_bounds__(512) void attn_kernel(
    const float* __restrict__ kT,     // [DD][NROW]
    const float* __restrict__ vbuf,   // [NROW][DD]
    const float* __restrict__ qbuf,   // [BB*TT][DD]
    const float* __restrict__ qb,     // [BB*TT][TT]
    float* __restrict__ out)          // [BB*TT][DD]
{
    __shared__ __align__(8) float qsT[DD][2];        // [d][m]
    __shared__ __align__(8) float weiT[TT][2];       // [t][m]
    __shared__ float red[16];
    __shared__ float invs[2];
    __shared__ float partial[8][2][DD];

    const int tid  = threadIdx.x;
    const int lane = tid & 63;
    const int wv   = tid >> 6;          // 0..7
    const int blk  = blockIdx.x;        // 0..1023
    const int b    = blk >> 8;
    const int w0   = (blk & 255) * 2;

    if (tid < 2 * DD) {
        const int m = tid >> 6, dd = tid & 63;
        qsT[dd][m] = qbuf[((size_t)b * TT + w0 + m) * DD + dd];
    }
    __syncthreads();

    // ---- phase 1: logits for t = tid, m in {0,1} ----
    {
        const int t = tid;
        const float* kcol = kT + (size_t)b * SS + w0 + t;
        const float* qbp  = qb + ((size_t)b * TT + w0) * TT + t;
        float a0 = qbp[0];
        float a1 = qbp[TT];
#pragma unroll 8
        for (int dd = 0; dd < DD; ++dd) {
            const float* kr = kcol + (size_t)dd * NROW;
            const float q0 = qsT[dd][0], q1 = qsT[dd][1];
            a0 = fmaf(q0, kr[0], a0);
            a1 = fmaf(q1, kr[1], a1);
        }
        weiT[t][0] = a0;
        weiT[t][1] = a1;
    }
    __syncthreads();

    // ---- softmax: wave wv -> row m = wv>>2, quarter qt = wv&3 ----
    {
        const int m = wv >> 2, qt = wv & 3;
        const int tb = qt * 128 + lane;
        float r0 = weiT[tb][m], r1 = weiT[tb + 64][m];
        float mx = fmaxf(r0, r1);
#pragma unroll
        for (int off = 1; off < 64; off <<= 1)
            mx = fmaxf(mx, __shfl_xor(mx, off, 64));
        if (lane == 0) red[wv] = mx;
        __syncthreads();
        mx = fmaxf(fmaxf(red[m * 4], red[m * 4 + 1]),
                   fmaxf(red[m * 4 + 2], red[m * 4 + 3]));
        const float e0 = __expf(r0 - mx), e1 = __expf(r1 - mx);
        weiT[tb][m] = e0;
        weiT[tb + 64][m] = e1;
        float sum = e0 + e1;
#pragma unroll
        for (int off = 1; off < 64; off <<= 1)
            sum += __shfl_xor(sum, off, 64);
        if (lane == 0) red[8 + wv] = sum;
        __syncthreads();
        if (tid < 2)
            invs[tid] = 1.f / (red[8 + tid * 4] + red[9 + tid * 4] +
                               red[10 + tid * 4] + red[11 + tid * 4]);
    }
    __syncthreads();

    // ---- phase 2: PV, wave wv covers 64 t, sliding v register ----
    {
        const int t0r = wv * 64;
        const float* vb = vbuf + ((size_t)b * SS + w0 + t0r) * DD + lane;
        float p0 = 0.f, p1 = 0.f;
        float v0 = vb[0];
#pragma unroll 4
        for (int t = 0; t < 64; ++t) {
            const float v1 = vb[(size_t)(t + 1) * DD];
            const f2 w2 = *(const f2*)&weiT[t0r + t][0];
            p0 = fmaf(w2[0], v0, p0);
            p1 = fmaf(w2[1], v1, p1);
            v0 = v1;
        }
        partial[wv][0][lane] = p0;
        partial[wv][1][lane] = p1;
    }
    __syncthreads();

    // ---- final reduce + store ----
    if (tid < 2 * DD) {
        const int m = tid >> 6, dd = tid & 63;
        float o = 0.f;
#pragma unroll
        for (int j = 0; j < 8; ++j) o += partial[j][m][dd];
        out[((size_t)b * TT + w0 + m) * DD + dd] = o * invs[m];
    }
}

// ---------------------------------------------------------------------------
extern "C" void kernel_launch(void* const* d_in, const int* in_sizes, int n_in,
                              void* d_out, int out_size, void* d_ws, size_t ws_size,
                              hipStream_t stream) {
    const float* x    = (const float*)d_in[0];
    const float* Wk   = (const float*)d_in[1];
    const float* Wv   = (const float*)d_in[2];
    const float* Wq   = (const float*)d_in[3];
    const float* bias = (const float*)d_in[4];
    float* out = (float*)d_out;

    char* ws = (char*)d_ws;
    float* kT             = (float*)(ws + 0);                 // 1.05 MB
    float* vbuf           = (float*)(ws + (2u  << 20));       // 1.05 MB
    float* qbuf           = (float*)(ws + (4u  << 20));       // 0.52 MB
    float* qb             = (float*)(ws + (8u  << 20));       // 4 MB
    unsigned short* xh    = (unsigned short*)(ws + (16u << 20));  // 8.4 MB
    unsigned short* xl    = (unsigned short*)(ws + (32u << 20));  // 8.4 MB
    unsigned short* bwh   = (unsigned short*)(ws + (48u << 20));  // 0.39 MB
    unsigned short* bwl   = (unsigned short*)(ws + (52u << 20));  // 0.39 MB

    xsplit_kernel<<<NROW * CC / 4 / 512, 512, 0, stream>>>(x, xh, xl);
    wsplit_kernel<<<384, 64, 0, stream>>>(Wk, Wv, Wq, bwh, bwl);
    proj_mfma_kernel<<<768, 64, 0, stream>>>(xh, xl, bwh, bwl, kT, vbuf, qbuf);
    qbias_kernel<<<BB * TT / 4, 512, 0, stream>>>(qbuf, bias, qb);
    attn_kernel<<<BB * TT / 2, 512, 0, stream>>>(kT, vbuf, qbuf, qb, out);
}

// Round 13
// 122.278 us; speedup vs baseline: 5.7579x; 1.0308x over previous
//
#include <hip/hip_runtime.h>
#include <hip/hip_bf16.h>

#define BB 4      // batch
#define SS 1023   // source length = 2T-1
#define TT 512    // window length
#define CC 1024   // embed dim
#define DD 64     // head size
#define NROW (BB*SS)    // 4092

typedef float f4 __attribute__((ext_vector_type(4)));
typedef float f2 __attribute__((ext_vector_type(2)));
typedef short bf16x8 __attribute__((ext_vector_type(8)));
typedef float f32x4 __attribute__((ext_vector_type(4)));

// round-to-nearest-even bf16 split: v ~= hi + lo, both bf16 (packed u32 lo<<16|hi)
__device__ __forceinline__ unsigned split_rtn(float v) {
    const unsigned u  = __builtin_bit_cast(unsigned, v);
    const unsigned r  = u + 0x7FFFu + ((u >> 16) & 1u);
    const unsigned hi = r >> 16;
    const float hif   = __builtin_bit_cast(float, r & 0xFFFF0000u);
    const float res   = v - hif;                       // exact
    const unsigned u2 = __builtin_bit_cast(unsigned, res);
    const unsigned r2 = u2 + 0x7FFFu + ((u2 >> 16) & 1u);
    return (r2 & 0xFFFF0000u) | hi;                    // lo<<16 | hi
}

// ---------------------------------------------------------------------------
// Kernel 1: split W{k,v,q} into B-fragment-ordered bf16 hi/lo (RTN).
// Frag f = (p*4 + nsub)*32 + ks. Lane holds B[k=ks*32+(lane>>4)*8+j]
// [n=nsub*16+(lane&15)], j=0..7: bw[f*512 + lane*8 + j].
// ---------------------------------------------------------------------------
__global__ __launch_bounds__(64) void wsplit_kernel(
    const float* __restrict__ Wk,
    const float* __restrict__ Wv,
    const float* __restrict__ Wq,
    unsigned short* __restrict__ bwh,
    unsigned short* __restrict__ bwl)
{
    const int f    = blockIdx.x;        // 0..383
    const int p    = f >> 7;
    const int rem  = f & 127;
    const int nsub = rem >> 5;
    const int ks   = rem & 31;
    const int lane = threadIdx.x;
    const int quad = lane >> 4, l4 = lane & 15;
    const float* W = (p == 0) ? Wk : (p == 1) ? Wv : Wq;
    const int n = nsub * 16 + l4;

    bf16x8 h, l;
#pragma unroll
    for (int j = 0; j < 8; ++j) {
        const int k = ks * 32 + quad * 8 + j;
        const unsigned hl = split_rtn(W[k * DD + n]);
        h[j] = (short)(hl & 0xFFFFu);
        l[j] = (short)(hl >> 16);
    }
    ((bf16x8*)bwh)[f * 64 + lane] = h;
    ((bf16x8*)bwl)[f * 64 + lane] = l;
}

// ---------------------------------------------------------------------------
// Kernel 2: projections via MFMA 16x16x32 bf16, full split product,
// x split IN-REGISTER from fp32 (no xsplit pass). 1536 single-wave blocks:
// blk -> (nh = blk&1, p = (blk>>1)%3, mt = (blk>>1)/3). Wave computes
// 16 rows x 32 cols (n-half nh) of projection p.
// A: lane loads x[bs0+(lane&15)][ks*32+(lane>>4)*8 + 0..7] as 2 f4 loads,
// splits to ah/al bf16x8. B: coalesced 16B loads from wsplit output.
// C/D layout (verified): row = (lane>>4)*4 + reg, col = lane&15.
// ---------------------------------------------------------------------------
__global__ __launch_bounds__(64) void proj_mfma_kernel(
    const float* __restrict__ x,
    const unsigned short* __restrict__ bwh,
    const unsigned short* __restrict__ bwl,
    float* __restrict__ kT,     // [DD][NROW]
    float* __restrict__ vbuf,   // [NROW][DD]
    float* __restrict__ qbuf)   // [BB*TT][DD]
{
    const int blk  = blockIdx.x;        // 0..1535
    const int nh   = blk & 1;
    const int pm   = blk >> 1;          // 0..767
    const int p    = pm % 3;
    const int mt   = pm / 3;            // 0..255
    const int bs0  = mt * 16;
    const int lane = threadIdx.x;
    const int quad = lane >> 4, l4 = lane & 15;
    const int nsub0 = nh * 2;

    int arow = bs0 + l4; if (arow > NROW - 1) arow = NROW - 1;   // pad clamp
    const float* ap = x + (size_t)arow * CC;
    const bf16x8* bh = (const bf16x8*)bwh
                     + (size_t)((p * 4 + nsub0) * 32) * 64 + lane;
    const bf16x8* bl = (const bf16x8*)bwl
                     + (size_t)((p * 4 + nsub0) * 32) * 64 + lane;

    f32x4 acc0 = {0.f,0.f,0.f,0.f}, acc1 = {0.f,0.f,0.f,0.f};

#pragma unroll 4
    for (int ks = 0; ks < 32; ++ks) {
        const int k0 = ks * 32 + quad * 8;
        const f4 xa = *(const f4*)(ap + k0);
        const f4 xb = *(const f4*)(ap + k0 + 4);
        bf16x8 ah, al;
#pragma unroll
        for (int j = 0; j < 4; ++j) {
            const unsigned hl = split_rtn(xa[j]);
            ah[j] = (short)(hl & 0xFFFFu);
            al[j] = (short)(hl >> 16);
        }
#pragma unroll
        for (int j = 0; j < 4; ++j) {
            const unsigned hl = split_rtn(xb[j]);
            ah[4 + j] = (short)(hl & 0xFFFFu);
            al[4 + j] = (short)(hl >> 16);
        }
        const bf16x8 bh0 = bh[(0 * 32 + ks) * 64];
        const bf16x8 bh1 = bh[(1 * 32 + ks) * 64];
        const bf16x8 bl0 = bl[(0 * 32 + ks) * 64];
        const bf16x8 bl1 = bl[(1 * 32 + ks) * 64];

        acc0 = __builtin_amdgcn_mfma_f32_16x16x32_bf16(ah, bh0, acc0, 0, 0, 0);
        acc1 = __builtin_amdgcn_mfma_f32_16x16x32_bf16(ah, bh1, acc1, 0, 0, 0);
        acc0 = __builtin_amdgcn_mfma_f32_16x16x32_bf16(ah, bl0, acc0, 0, 0, 0);
        acc1 = __builtin_amdgcn_mfma_f32_16x16x32_bf16(ah, bl1, acc1, 0, 0, 0);
        acc0 = __builtin_amdgcn_mfma_f32_16x16x32_bf16(al, bh0, acc0, 0, 0, 0);
        acc1 = __builtin_amdgcn_mfma_f32_16x16x32_bf16(al, bh1, acc1, 0, 0, 0);
        acc0 = __builtin_amdgcn_mfma_f32_16x16x32_bf16(al, bl0, acc0, 0, 0, 0);
        acc1 = __builtin_amdgcn_mfma_f32_16x16x32_bf16(al, bl1, acc1, 0, 0, 0);
    }

    // ---- epilogue: D[row=quad*4+reg][col=l4], d = nsub*16 + l4 ----
#pragma unroll
    for (int s = 0; s < 2; ++s) {
        const f32x4 a = s ? acc1 : acc0;
        const int d = (nsub0 + s) * 16 + l4;
#pragma unroll
        for (int reg = 0; reg < 4; ++reg) {
            const int bs = bs0 + quad * 4 + reg;
            if (bs < NROW) {
                const float val = a[reg];
                if (p == 0) {
                    kT[(size_t)d * NROW + bs] = val;
                } else if (p == 1) {
                    vbuf[(size_t)bs * DD + d] = val;
                } else {
                    const int b = bs / SS, ss = bs - b * SS;
                    if (ss >= TT - 1)
                        qbuf[((size_t)b * TT + (ss - (TT - 1))) * DD + d] = val;
                }
            }
        }
    }
}

// ---------------------------------------------------------------------------
// Kernel 3: qb[b,w,t] = sum_d q[b,w,d] * bias[d,t]  (round-10 proven).
// ---------------------------------------------------------------------------
__global__ __launch_bounds__(512) void qbias_kernel(
    const float* __restrict__ qbuf,   // [BB*TT][DD]
    const float* __restrict__ bias,   // [DD][TT]
    float* __restrict__ qb)           // [BB*TT][TT]
{
    __shared__ __align__(16) float qsT[DD][4];   // [d][m]

    const int tid = threadIdx.x;
    const int blk = blockIdx.x;            // 0..511
    const int b   = blk >> 7;
    const int w0  = (blk & 127) * 4;

    if (tid < 4 * DD) {
        const int m = tid >> 6, dd = tid & 63;
        qsT[dd][m] = qbuf[((size_t)b * TT + w0 + m) * DD + dd];
    }
    __syncthreads();

    const int t = tid;
    f4 acc = {0.f, 0.f, 0.f, 0.f};
#pragma unroll 8
    for (int dd = 0; dd < DD; ++dd) {
        const float bb = bias[dd * TT + t];
        const f4 qv = *(const f4*)&qsT[dd][0];
        acc[0] = fmaf(qv[0], bb, acc[0]);
        acc[1] = fmaf(qv[1], bb, acc[1]);
        acc[2] = fmaf(qv[2], bb, acc[2]);
        acc[3] = fmaf(qv[3], bb, acc[3]);
    }
#pragma unroll
    for (int m = 0; m < 4; ++m)
        qb[((size_t)b * TT + w0 + m) * TT + t] = acc[m];
}

// ---------------------------------------------------------------------------
// Kernel 4: attention, WT=2 windows/block, 1024 blocks x 512 threads
// (round-10 proven version, qb-seeded logits).
// ---------------------------------------------------------------------------
__global__ __launch_bounds__(512) void attn_kernel(
    const float* __restrict__ kT,     // [DD][NROW]
    const float* __restrict__ vbuf,   // [NROW][DD]
    const float* __restrict__ qbuf,   // [BB*TT][DD]
    const float* __restrict__ qb,     // [BB*TT][TT]
    float* __restrict__ out)          // [BB*TT][DD]
{
    __shared__ __align__(8) float qsT[DD][2];        // [d][m]
    __shared__ __align__(8) float weiT[TT][2];       // [t][m]
    __shared__ float red[16];
    __shared__ float invs[2];
    __shared__ float partial[8][2][DD];

    const int tid  = threadIdx.x;
    const int lane = tid & 63;
    const int wv   = tid >> 6;          // 0..7
    const int blk  = blockIdx.x;        // 0..1023
    const int b    = blk >> 8;
    const int w0   = (blk & 255) * 2;

    if (tid < 2 * DD) {
        const int m = tid >> 6, dd = tid & 63;
        qsT[dd][m] = qbuf[((size_t)b * TT + w0 + m) * DD + dd];
    }
    __syncthreads();

    // ---- phase 1: logits for t = tid, m in {0,1} ----
    {
        const int t = tid;
        const float* kcol = kT + (size_t)b * SS + w0 + t;
        const float* qbp  = qb + ((size_t)b * TT + w0) * TT + t;
        float a0 = qbp[0];
        float a1 = qbp[TT];
#pragma unroll 8
        for (int dd = 0; dd < DD; ++dd) {
            const float* kr = kcol + (size_t)dd * NROW;
            const float q0 = qsT[dd][0], q1 = qsT[dd][1];
            a0 = fmaf(q0, kr[0], a0);
            a1 = fmaf(q1, kr[1], a1);
        }
        weiT[t][0] = a0;
        weiT[t][1] = a1;
    }
    __syncthreads();

    // ---- softmax: wave wv -> row m = wv>>2, quarter qt = wv&3 ----
    {
        const int m = wv >> 2, qt = wv & 3;
        const int tb = qt * 128 + lane;
        float r0 = weiT[tb][m], r1 = weiT[tb + 64][m];
        float mx = fmaxf(r0, r1);
#pragma unroll
        for (int off = 1; off < 64; off <<= 1)
            mx = fmaxf(mx, __shfl_xor(mx, off, 64));
        if (lane == 0) red[wv] = mx;
        __syncthreads();
        mx = fmaxf(fmaxf(red[m * 4], red[m * 4 + 1]),
                   fmaxf(red[m * 4 + 2], red[m * 4 + 3]));
        const float e0 = __expf(r0 - mx), e1 = __expf(r1 - mx);
        weiT[tb][m] = e0;
        weiT[tb + 64][m] = e1;
        float sum = e0 + e1;
#pragma unroll
        for (int off = 1; off < 64; off <<= 1)
            sum += __shfl_xor(sum, off, 64);
        if (lane == 0) red[8 + wv] = sum;
        __syncthreads();
        if (tid < 2)
            invs[tid] = 1.f / (red[8 + tid * 4] + red[9 + tid * 4] +
                               red[10 + tid * 4] + red[11 + tid * 4]);
    }
    __syncthreads();

    // ---- phase 2: PV, wave wv covers 64 t, sliding v register ----
    {
        const int t0r = wv * 64;
        const float* vb = vbuf + ((size_t)b * SS + w0 + t0r) * DD + lane;
        float p0 = 0.f, p1 = 0.f;
        float v0 = vb[0];
#pragma unroll 4
        for (int t = 0; t < 64; ++t) {
            const float v1 = vb[(size_t)(t + 1) * DD];
            const f2 w2 = *(const f2*)&weiT[t0r + t][0];
            p0 = fmaf(w2[0], v0, p0);
            p1 = fmaf(w2[1], v1, p1);
            v0 = v1;
        }
        partial[wv][0][lane] = p0;
        partial[wv][1][lane] = p1;
    }
    __syncthreads();

    // ---- final reduce + store ----
    if (tid < 2 * DD) {
        const int m = tid >> 6, dd = tid & 63;
        float o = 0.f;
#pragma unroll
        for (int j = 0; j < 8; ++j) o += partial[j][m][dd];
        out[((size_t)b * TT + w0 + m) * DD + dd] = o * invs[m];
    }
}

// ---------------------------------------------------------------------------
extern "C" void kernel_launch(void* const* d_in, const int* in_sizes, int n_in,
                              void* d_out, int out_size, void* d_ws, size_t ws_size,
                              hipStream_t stream) {
    const float* x    = (const float*)d_in[0];
    const float* Wk   = (const float*)d_in[1];
    const float* Wv   = (const float*)d_in[2];
    const float* Wq   = (const float*)d_in[3];
    const float* bias = (const float*)d_in[4];
    float* out = (float*)d_out;

    char* ws = (char*)d_ws;
    float* kT             = (float*)(ws + 0);                 // 1.05 MB
    float* vbuf           = (float*)(ws + (2u  << 20));       // 1.05 MB
    float* qbuf           = (float*)(ws + (4u  << 20));       // 0.52 MB
    float* qb             = (float*)(ws + (8u  << 20));       // 4 MB
    unsigned short* bwh   = (unsigned short*)(ws + (16u << 20));  // 0.39 MB
    unsigned short* bwl   = (unsigned short*)(ws + (20u << 20));  // 0.39 MB

    wsplit_kernel<<<384, 64, 0, stream>>>(Wk, Wv, Wq, bwh, bwl);
    proj_mfma_kernel<<<1536, 64, 0, stream>>>(x, bwh, bwl, kT, vbuf, qbuf);
    qbias_kernel<<<BB * TT / 4, 512, 0, stream>>>(qbuf, bias, qb);
    attn_kernel<<<BB * TT / 2, 512, 0, stream>>>(kT, vbuf, qbuf, qb, out);
}

// Round 17
// 118.226 us; speedup vs baseline: 5.9552x; 1.0343x over previous
//
#include <hip/hip_runtime.h>
#include <hip/hip_bf16.h>

#define BB 4      // batch
#define SS 1023   // source length = 2T-1
#define TT 512    // window length
#define CC 1024   // embed dim
#define DD 64     // head size
#define NROW (BB*SS)    // 4092
#define NROWP 4096      // padded kT row stride: kT[d][b*1024 + s]

typedef float f4 __attribute__((ext_vector_type(4)));
typedef float f2 __attribute__((ext_vector_type(2)));
typedef short bf16x8 __attribute__((ext_vector_type(8)));
typedef float f32x4 __attribute__((ext_vector_type(4)));

// RTN bf16 split: v ~= hi + lo (packed u32 lo<<16|hi).
// SESSION INVARIANT: this split + ALL FOUR MFMA products is the only
// verified-passing config (r12/r13: 0.0156). Manual trunc/half-up splits
// with al*bl dropped fail deterministically at ~0.18 (r14/r15/r16) for
// reasons not visible at source level. Do not "optimize" this again.
__device__ __forceinline__ unsigned split_rtn(float v) {
    const unsigned u  = __builtin_bit_cast(unsigned, v);
    const unsigned r  = u + 0x7FFFu + ((u >> 16) & 1u);
    const unsigned hi = r >> 16;
    const float hif   = __builtin_bit_cast(float, r & 0xFFFF0000u);
    const float res   = v - hif;
    const unsigned u2 = __builtin_bit_cast(unsigned, res);
    const unsigned r2 = u2 + 0x7FFFu + ((u2 >> 16) & 1u);
    return (r2 & 0xFFFF0000u) | hi;                    // lo<<16 | hi
}

// ---------------------------------------------------------------------------
// Kernel 1: split W{k,v,q} into B-fragment-ordered bf16 hi/lo (RTN).
// Frag f = (p*4 + nsub)*32 + ks. Lane holds B[k=ks*32+(lane>>4)*8+j]
// [n=nsub*16+(lane&15)], j=0..7: bw[f*512 + lane*8 + j].  (proven)
// ---------------------------------------------------------------------------
__global__ __launch_bounds__(64) void wsplit_kernel(
    const float* __restrict__ Wk,
    const float* __restrict__ Wv,
    const float* __restrict__ Wq,
    unsigned short* __restrict__ bwh,
    unsigned short* __restrict__ bwl)
{
    const int f    = blockIdx.x;        // 0..383
    const int p    = f >> 7;
    const int rem  = f & 127;
    const int nsub = rem >> 5;
    const int ks   = rem & 31;
    const int lane = threadIdx.x;
    const int quad = lane >> 4, l4 = lane & 15;
    const float* W = (p == 0) ? Wk : (p == 1) ? Wv : Wq;
    const int n = nsub * 16 + l4;

    bf16x8 h, l;
#pragma unroll
    for (int j = 0; j < 8; ++j) {
        const int k = ks * 32 + quad * 8 + j;
        const unsigned hl = split_rtn(W[k * DD + n]);
        h[j] = (short)(hl & 0xFFFFu);
        l[j] = (short)(hl >> 16);
    }
    ((bf16x8*)bwh)[f * 64 + lane] = h;
    ((bf16x8*)bwl)[f * 64 + lane] = l;
}

// ---------------------------------------------------------------------------
// Kernel 2: projections via MFMA 16x16x32 bf16 — r12-proposal VERBATIM
// (in-register split_rtn for x, FULL 8-MFMA product set; passed twice at
// absmax 0.0156). Only change: kT store address is PADDED kT[d][b*1024+s]
// (formula exonerated: r15 vs r16 identical absmax).
// 1536 single-wave blocks: blk -> (nh=blk&1, p=(blk>>1)%3, mt=(blk>>1)/3).
// C/D layout (verified): row = (lane>>4)*4 + reg, col = lane&15.
// ---------------------------------------------------------------------------
__global__ __launch_bounds__(64) void proj_mfma_kernel(
    const float* __restrict__ x,
    const unsigned short* __restrict__ bwh,
    const unsigned short* __restrict__ bwl,
    float* __restrict__ kT,     // [DD][NROWP] padded
    float* __restrict__ vbuf,   // [NROW][DD]
    float* __restrict__ qbuf)   // [BB*TT][DD]
{
    const int blk  = blockIdx.x;        // 0..1535
    const int nh   = blk & 1;
    const int pm   = blk >> 1;          // 0..767
    const int p    = pm % 3;
    const int mt   = pm / 3;            // 0..255
    const int bs0  = mt * 16;
    const int lane = threadIdx.x;
    const int quad = lane >> 4, l4 = lane & 15;
    const int nsub0 = nh * 2;

    int arow = bs0 + l4; if (arow > NROW - 1) arow = NROW - 1;   // pad clamp
    const float* ap = x + (size_t)arow * CC;
    const bf16x8* bh = (const bf16x8*)bwh
                     + (size_t)((p * 4 + nsub0) * 32) * 64 + lane;
    const bf16x8* bl = (const bf16x8*)bwl
                     + (size_t)((p * 4 + nsub0) * 32) * 64 + lane;

    f32x4 acc0 = {0.f,0.f,0.f,0.f}, acc1 = {0.f,0.f,0.f,0.f};

#pragma unroll 4
    for (int ks = 0; ks < 32; ++ks) {
        const int k0 = ks * 32 + quad * 8;
        const f4 xa = *(const f4*)(ap + k0);
        const f4 xb = *(const f4*)(ap + k0 + 4);
        bf16x8 ah, al;
#pragma unroll
        for (int j = 0; j < 4; ++j) {
            const unsigned hl = split_rtn(xa[j]);
            ah[j] = (short)(hl & 0xFFFFu);
            al[j] = (short)(hl >> 16);
        }
#pragma unroll
        for (int j = 0; j < 4; ++j) {
            const unsigned hl = split_rtn(xb[j]);
            ah[4 + j] = (short)(hl & 0xFFFFu);
            al[4 + j] = (short)(hl >> 16);
        }
        const bf16x8 bh0 = bh[(0 * 32 + ks) * 64];
        const bf16x8 bh1 = bh[(1 * 32 + ks) * 64];
        const bf16x8 bl0 = bl[(0 * 32 + ks) * 64];
        const bf16x8 bl1 = bl[(1 * 32 + ks) * 64];

        acc0 = __builtin_amdgcn_mfma_f32_16x16x32_bf16(ah, bh0, acc0, 0, 0, 0);
        acc1 = __builtin_amdgcn_mfma_f32_16x16x32_bf16(ah, bh1, acc1, 0, 0, 0);
        acc0 = __builtin_amdgcn_mfma_f32_16x16x32_bf16(ah, bl0, acc0, 0, 0, 0);
        acc1 = __builtin_amdgcn_mfma_f32_16x16x32_bf16(ah, bl1, acc1, 0, 0, 0);
        acc0 = __builtin_amdgcn_mfma_f32_16x16x32_bf16(al, bh0, acc0, 0, 0, 0);
        acc1 = __builtin_amdgcn_mfma_f32_16x16x32_bf16(al, bh1, acc1, 0, 0, 0);
        acc0 = __builtin_amdgcn_mfma_f32_16x16x32_bf16(al, bl0, acc0, 0, 0, 0);
        acc1 = __builtin_amdgcn_mfma_f32_16x16x32_bf16(al, bl1, acc1, 0, 0, 0);
    }

    // ---- epilogue: D[row=quad*4+reg][col=l4], d = nsub*16 + l4 ----
#pragma unroll
    for (int s = 0; s < 2; ++s) {
        const f32x4 a = s ? acc1 : acc0;
        const int d = (nsub0 + s) * 16 + l4;
#pragma unroll
        for (int reg = 0; reg < 4; ++reg) {
            const int bs = bs0 + quad * 4 + reg;
            if (bs < NROW) {
                const float val = a[reg];
                const int b = bs / SS, ss = bs - b * SS;
                if (p == 0) {
                    kT[(size_t)d * NROWP + b * 1024 + ss] = val;   // padded
                } else if (p == 1) {
                    vbuf[(size_t)bs * DD + d] = val;
                } else {
                    if (ss >= TT - 1)
                        qbuf[((size_t)b * TT + (ss - (TT - 1))) * DD + d] = val;
                }
            }
        }
    }
}

// ---------------------------------------------------------------------------
// Kernel 3: qb[b,w,t] = sum_d q[b,w,d] * bias[d,t]  (round-10 proven).
// ---------------------------------------------------------------------------
__global__ __launch_bounds__(512) void qbias_kernel(
    const float* __restrict__ qbuf,   // [BB*TT][DD]
    const float* __restrict__ bias,   // [DD][TT]
    float* __restrict__ qb)           // [BB*TT][TT]
{
    __shared__ __align__(16) float qsT[DD][4];   // [d][m]

    const int tid = threadIdx.x;
    const int blk = blockIdx.x;            // 0..511
    const int b   = blk >> 7;
    const int w0  = (blk & 127) * 4;

    if (tid < 4 * DD) {
        const int m = tid >> 6, dd = tid & 63;
        qsT[dd][m] = qbuf[((size_t)b * TT + w0 + m) * DD + dd];
    }
    __syncthreads();

    const int t = tid;
    f4 acc = {0.f, 0.f, 0.f, 0.f};
#pragma unroll 8
    for (int dd = 0; dd < DD; ++dd) {
        const float bb = bias[dd * TT + t];
        const f4 qv = *(const f4*)&qsT[dd][0];
        acc[0] = fmaf(qv[0], bb, acc[0]);
        acc[1] = fmaf(qv[1], bb, acc[1]);
        acc[2] = fmaf(qv[2], bb, acc[2]);
        acc[3] = fmaf(qv[3], bb, acc[3]);
    }
#pragma unroll
    for (int m = 0; m < 4; ++m)
        qb[((size_t)b * TT + w0 + m) * TT + t] = acc[m];
}

// ---------------------------------------------------------------------------
// Kernel 4: attention, WT=2 windows/block, 1024 blocks x 512 threads.
// Phase 1 (exonerated f2 version): thread (h=tid>>8, p=tid&255) computes 4
// logits (t=2p,2p+1 x m=0,1) over dd in [32h,32h+32) with two f2 k-loads/dd
// (padded kT -> 8B aligned); partials combined across h in LDS part[h][m][t].
// Softmax: wave wv -> row m=wv>>2, quarter wv&3. Phase 2: sliding v register.
// ---------------------------------------------------------------------------
__global__ __launch_bounds__(512) void attn_kernel(
    const float* __restrict__ kT,     // [DD][NROWP] padded
    const float* __restrict__ vbuf,   // [NROW][DD]
    const float* __restrict__ qbuf,   // [BB*TT][DD]
    const float* __restrict__ qb,     // [BB*TT][TT]
    float* __restrict__ out)          // [BB*TT][DD]
{
    __shared__ __align__(8) float qsT[DD][2];        // [d][m]
    __shared__ __align__(8) float part[2][2][TT];    // [h][m][t]  8 KB
    __shared__ __align__(8) float weiT[TT][2];       // [t][m]     4 KB
    __shared__ float red[16];
    __shared__ float invs[2];
    __shared__ float partial[8][2][DD];              // 4 KB

    const int tid  = threadIdx.x;
    const int lane = tid & 63;
    const int wv   = tid >> 6;          // 0..7
    const int blk  = blockIdx.x;        // 0..1023
    const int b    = blk >> 8;
    const int w0   = (blk & 255) * 2;

    if (tid < 2 * DD) {
        const int m = tid >> 6, dd = tid & 63;
        qsT[dd][m] = qbuf[((size_t)b * TT + w0 + m) * DD + dd];
    }
    __syncthreads();

    // ---- phase 1 ----
    {
        const int h = tid >> 8, p = tid & 255;
        const int t0 = 2 * p;
        const float* kcol = kT + (size_t)(32 * h) * NROWP + b * 1024 + w0 + t0;
        float a00, a01, a10, a11;   // a[m][j], t = t0 + j
        if (h == 0) {
            const float* qbp = qb + ((size_t)b * TT + w0) * TT + t0;
            const f2 q0v = *(const f2*)qbp;
            const f2 q1v = *(const f2*)(qbp + TT);
            a00 = q0v[0]; a01 = q0v[1]; a10 = q1v[0]; a11 = q1v[1];
        } else {
            a00 = a01 = a10 = a11 = 0.f;
        }
#pragma unroll 8
        for (int i = 0; i < 32; ++i) {
            const int dd = 32 * h + i;
            const float* kr = kcol + (size_t)i * NROWP;
            const f2 kA = *(const f2*)kr;         // k[w0+t0], k[w0+t0+1]
            const f2 kB = *(const f2*)(kr + 2);   // k[w0+t0+2]
            const float q0 = qsT[dd][0], q1 = qsT[dd][1];
            a00 = fmaf(q0, kA[0], a00);
            a01 = fmaf(q0, kA[1], a01);
            a10 = fmaf(q1, kA[1], a10);
            a11 = fmaf(q1, kB[0], a11);
        }
        *(f2*)&part[h][0][t0] = (f2){a00, a01};
        *(f2*)&part[h][1][t0] = (f2){a10, a11};
    }
    __syncthreads();

    // ---- softmax: wave wv -> row m = wv>>2, quarter qt = wv&3 ----
    {
        const int m = wv >> 2, qt = wv & 3;
        const int tb = qt * 128 + lane;
        float r0 = part[0][m][tb]      + part[1][m][tb];
        float r1 = part[0][m][tb + 64] + part[1][m][tb + 64];
        float mx = fmaxf(r0, r1);
#pragma unroll
        for (int off = 1; off < 64; off <<= 1)
            mx = fmaxf(mx, __shfl_xor(mx, off, 64));
        if (lane == 0) red[wv] = mx;
        __syncthreads();
        mx = fmaxf(fmaxf(red[m * 4], red[m * 4 + 1]),
                   fmaxf(red[m * 4 + 2], red[m * 4 + 3]));
        const float e0 = __expf(r0 - mx), e1 = __expf(r1 - mx);
        weiT[tb][m] = e0;
        weiT[tb + 64][m] = e1;
        float sum = e0 + e1;
#pragma unroll
        for (int off = 1; off < 64; off <<= 1)
            sum += __shfl_xor(sum, off, 64);
        if (lane == 0) red[8 + wv] = sum;
        __syncthreads();
        if (tid < 2)
            invs[tid] = 1.f / (red[8 + tid * 4] + red[9 + tid * 4] +
                               red[10 + tid * 4] + red[11 + tid * 4]);
    }
    __syncthreads();

    // ---- phase 2: PV, wave wv covers 64 t, sliding v register ----
    {
        const int t0r = wv * 64;
        const float* vb = vbuf + ((size_t)b * SS + w0 + t0r) * DD + lane;
        float p0 = 0.f, p1 = 0.f;
        float v0 = vb[0];
#pragma unroll 4
        for (int t = 0; t < 64; ++t) {
            const float v1 = vb[(size_t)(t + 1) * DD];
            const f2 w2 = *(const f2*)&weiT[t0r + t][0];
            p0 = fmaf(w2[0], v0, p0);
            p1 = fmaf(w2[1], v1, p1);
            v0 = v1;
        }
        partial[wv][0][lane] = p0;
        partial[wv][1][lane] = p1;
    }
    __syncthreads();

    // ---- final reduce + store ----
    if (tid < 2 * DD) {
        const int m = tid >> 6, dd = tid & 63;
        float o = 0.f;
#pragma unroll
        for (int j = 0; j < 8; ++j) o += partial[j][m][dd];
        out[((size_t)b * TT + w0 + m) * DD + dd] = o * invs[m];
    }
}

// ---------------------------------------------------------------------------
extern "C" void kernel_launch(void* const* d_in, const int* in_sizes, int n_in,
                              void* d_out, int out_size, void* d_ws, size_t ws_size,
                              hipStream_t stream) {
    const float* x    = (const float*)d_in[0];
    const float* Wk   = (const float*)d_in[1];
    const float* Wv   = (const float*)d_in[2];
    const float* Wq   = (const float*)d_in[3];
    const float* bias = (const float*)d_in[4];
    float* out = (float*)d_out;

    char* ws = (char*)d_ws;
    float* kT             = (float*)(ws + 0);                 // DD*4096*4 = 1 MB
    float* vbuf           = (float*)(ws + (2u  << 20));       // 1.05 MB
    float* qbuf           = (float*)(ws + (4u  << 20));       // 0.52 MB
    float* qb             = (float*)(ws + (8u  << 20));       // 4 MB
    unsigned short* bwh   = (unsigned short*)(ws + (16u << 20));  // 0.39 MB
    unsigned short* bwl   = (unsigned short*)(ws + (20u << 20));  // 0.39 MB

    wsplit_kernel<<<384, 64, 0, stream>>>(Wk, Wv, Wq, bwh, bwl);
    proj_mfma_kernel<<<1536, 64, 0, stream>>>(x, bwh, bwl, kT, vbuf, qbuf);
    qbias_kernel<<<BB * TT / 4, 512, 0, stream>>>(qbuf, bias, qb);
    attn_kernel<<<BB * TT / 2, 512, 0, stream>>>(kT, vbuf, qbuf, qb, out);
}